// Round 1
// baseline (328.183 us; speedup 1.0000x reference)
//
#include <hip/hip_runtime.h>
#include <math.h>

#define TOPK 8
#define D    256
#define VOCAB 5000
#define BSZ  64
#define SEQ  128
#define ROWS (BSZ*SEQ)     /* 8192 rows of na_pred */

/* ---------------- workspace layout (bytes) ---------------- */
#define OFF_IDX   0          /* int32  ROWS*8      = 262144 B */
#define OFF_NPP   262144     /* f32    ROWS*8      = 262144 B */
#define OFF_M     524288     /* f32    256*256     = 262144 B */
#define OFF_U     786432     /* f32    256         */
#define OFF_W     787456     /* f32    256         */
#define OFF_P     790528     /* f32    5000*256    = 5,120,000 B */
#define OFF_NPART 5910528    /* f32    BSZ*SEQ*2*8 = 524288 B */
#define WS_NEED   (OFF_NPART + 524288)

/* d_out layout (floats) */
#define OUT_SCORED 0         /* (b,S,D)  2097152 */
#define OUT_PS     2097152   /* (b,S,8)  65536   */
#define OUT_IDX    2162688   /* (b,S,8)  65536   */

/* ============ kernel 1: row softmax stats + top-8 ============ */
__global__ __launch_bounds__(256) void topk_kernel(
    const float* __restrict__ na_pred,
    int*  __restrict__ out_idx,
    float* __restrict__ out_npp,
    float* __restrict__ out_idx_f)
{
    __shared__ float row[VOCAB];
    __shared__ float rv[256];
    __shared__ int   ri[256];
    __shared__ float topv[TOPK];
    __shared__ int   topi[TOPK];

    const int tid = threadIdx.x;
    const long long base = (long long)blockIdx.x * VOCAB;
    const float4* src4 = (const float4*)(na_pred + base);
    for (int i = tid; i < VOCAB/4; i += 256)
        ((float4*)row)[i] = src4[i];
    __syncthreads();

    /* row max */
    float mx = -INFINITY;
    for (int i = tid; i < VOCAB; i += 256) mx = fmaxf(mx, row[i]);
    rv[tid] = mx; __syncthreads();
    for (int off = 128; off > 0; off >>= 1) {
        if (tid < off) rv[tid] = fmaxf(rv[tid], rv[tid+off]);
        __syncthreads();
    }
    const float rmax = rv[0]; __syncthreads();

    /* sum exp */
    float se = 0.f;
    for (int i = tid; i < VOCAB; i += 256) se += __expf(row[i] - rmax);
    rv[tid] = se; __syncthreads();
    for (int off = 128; off > 0; off >>= 1) {
        if (tid < off) rv[tid] += rv[tid+off];
        __syncthreads();
    }
    const float sumexp = rv[0]; __syncthreads();

    /* 8 rounds of block argmax (tie -> smaller index, matches lax.top_k) */
    for (int r = 0; r < TOPK; ++r) {
        float bv = -INFINITY; int bi = VOCAB;
        for (int i = tid; i < VOCAB; i += 256) {
            float v = row[i];
            if (v > bv) { bv = v; bi = i; }
        }
        rv[tid] = bv; ri[tid] = bi; __syncthreads();
        for (int off = 128; off > 0; off >>= 1) {
            if (tid < off) {
                float v2 = rv[tid+off]; int i2 = ri[tid+off];
                if (v2 > rv[tid] || (v2 == rv[tid] && i2 < ri[tid])) {
                    rv[tid] = v2; ri[tid] = i2;
                }
            }
            __syncthreads();
        }
        if (tid == 0) { topv[r] = rv[0]; topi[r] = ri[0]; row[ri[0]] = -INFINITY; }
        __syncthreads();
    }

    if (tid == 0) {
        float p[TOPK], q[TOPK];
        float pm = -INFINITY;
        #pragma unroll
        for (int r = 0; r < TOPK; ++r) {
            p[r] = __expf(topv[r] - rmax) / sumexp;
            pm = fmaxf(pm, p[r]);
        }
        float s2 = 0.f;
        #pragma unroll
        for (int r = 0; r < TOPK; ++r) { q[r] = __expf(p[r] - pm); s2 += q[r]; }
        const long long ob = (long long)blockIdx.x * TOPK;
        #pragma unroll
        for (int r = 0; r < TOPK; ++r) {
            out_idx[ob + r]   = topi[r];
            out_npp[ob + r]   = q[r] / s2;
            out_idx_f[ob + r] = (float)topi[r];
        }
    }
}

/* ============ kernel 2: M = Wq @ Wk^T ============ */
__global__ __launch_bounds__(256) void m_kernel(
    const float* __restrict__ Wq, const float* __restrict__ Wk,
    float* __restrict__ M)
{
    __shared__ float qrow[D];
    const int a = blockIdx.x, j = threadIdx.x;
    qrow[j] = Wq[a*D + j];
    __syncthreads();
    const float* wkr = Wk + j*D;
    float acc = 0.f;
    for (int d = 0; d < D; ++d) acc += qrow[d] * wkr[d];
    M[a*D + j] = acc;
}

/* ============ kernel 2b: u = Wq@bk, w = Wk@bq ============ */
__global__ __launch_bounds__(256) void bias_kernel(
    const float* __restrict__ Wq, const float* __restrict__ Wk,
    const float* __restrict__ bq, const float* __restrict__ bk,
    float* __restrict__ u, float* __restrict__ w)
{
    const int i = threadIdx.x;
    float au = 0.f, aw = 0.f;
    for (int d = 0; d < D; ++d) {
        au += Wq[i*D + d] * bk[d];
        aw += Wk[i*D + d] * bq[d];
    }
    u[i] = au; w[i] = aw;
}

/* ============ kernel 3: P = E @ M  (16 vocab rows / block) ============ */
__global__ __launch_bounds__(256) void p_kernel(
    const float* __restrict__ E, const float* __restrict__ M,
    float* __restrict__ P)
{
    __shared__ float se[16][D];
    const int j  = threadIdx.x;
    const int r0 = blockIdx.x * 16;
    const int nr = min(16, VOCAB - r0);
    for (int r = 0; r < 16; ++r)
        se[r][j] = (r < nr) ? E[(long long)(r0+r)*D + j] : 0.f;
    __syncthreads();
    float acc[16];
    #pragma unroll
    for (int r = 0; r < 16; ++r) acc[r] = 0.f;
    for (int d = 0; d < D; ++d) {
        const float m = M[d*D + j];
        #pragma unroll
        for (int r = 0; r < 16; ++r) acc[r] += se[r][d] * m;
    }
    for (int r = 0; r < nr; ++r) P[(long long)(r0+r)*D + j] = acc[r];
}

/* ============ kernel 4: masked block attention -> na_part ============ */
__global__ __launch_bounds__(128) void attn_kernel(
    const float* __restrict__ P, const float* __restrict__ E,
    const int*  __restrict__ idx, const float* __restrict__ w,
    float* __restrict__ na_part /* (BSZ,SEQ,2,8) */)
{
    const int blk = blockIdx.x;
    const int b = blk / SEQ, s = blk % SEQ;
    const int tid = threadIdx.x;

    __shared__ int   kch[2];
    __shared__ int   qidx[8];
    __shared__ int   kidx[16];
    __shared__ float Ps[8][D+1];
    __shared__ float Es[16][D+1];
    __shared__ float kb[16];
    __shared__ float Ss[8][17];

    int nk = 0;
    if (s - 1 >= 0)  { if (tid == 0) kch[nk] = s-1; nk++; }
    /* careful: compute nk uniformly */
    nk = 0;
    int kcl[2];
    if (s - 1 >= 0)  kcl[nk++] = s - 1;
    if (s + 1 < SEQ) kcl[nk++] = s + 1;
    if (tid < nk) kch[tid] = kcl[tid];
    const int nkeys = nk * 8;

    if (tid < 8)  qidx[tid] = idx[(long long)blk*8 + tid];
    if (tid < nkeys) kidx[tid] = idx[((long long)(b*SEQ + kcl[tid>>3]))*8 + (tid & 7)];
    __syncthreads();

    /* stage P rows (queries) and E rows (keys) */
    const int tot = (8 + nkeys) * D;
    for (int i = tid; i < tot; i += 128) {
        const int r = i / D, d = i % D;
        if (r < 8) Ps[r][d] = P[(long long)qidx[r]*D + d];
        else       Es[r-8][d] = E[(long long)kidx[r-8]*D + d];
    }
    __syncthreads();

    /* key-side bias term (zero for this benchmark's bq, kept for exactness) */
    if (tid < nkeys) {
        float a = 0.f;
        for (int d = 0; d < D; ++d) a += Es[tid][d] * w[d];
        kb[tid] = a;
    }
    __syncthreads();

    /* scores: 8 x nkeys */
    if (tid < 8 * nkeys) {
        const int qi = tid / nkeys, ki = tid % nkeys;
        float acc = 0.f;
        for (int d = 0; d < D; ++d) acc += Ps[qi][d] * Es[ki][d];
        Ss[qi][ki] = 16.f * acc + kb[ki];
    }
    __syncthreads();

    /* per-query softmax over its allowed keys */
    if (tid < 8) {
        float m = -INFINITY;
        for (int ki = 0; ki < nkeys; ++ki) m = fmaxf(m, Ss[tid][ki]);
        float sum = 0.f;
        for (int ki = 0; ki < nkeys; ++ki) {
            const float e = __expf(Ss[tid][ki] - m);
            Ss[tid][ki] = e; sum += e;
        }
        const float inv = 1.f / sum;
        for (int ki = 0; ki < nkeys; ++ki) Ss[tid][ki] *= inv;
    }
    __syncthreads();

    /* column sums -> deterministic scatter into na_part */
    if (tid < nkeys) {
        float cs = 0.f;
        #pragma unroll
        for (int qi = 0; qi < 8; ++qi) cs += Ss[qi][tid];
        const int kc = kch[tid >> 3];
        const int slot = (kc == s + 1) ? 0 : 1;   /* query chunk = kc-1 -> slot0, kc+1 -> slot1 */
        na_part[(((long long)(b*SEQ + kc))*2 + slot)*8 + (tid & 7)] = cs;
    }
}

/* ============ kernel 5: finalize ============ */
__global__ __launch_bounds__(256) void finalize_kernel(
    const float* __restrict__ E, const int* __restrict__ idx,
    const float* __restrict__ npp, const float* __restrict__ na_part,
    float* __restrict__ out)
{
    const int blk = blockIdx.x;           /* b*SEQ + s */
    const int tid = threadIdx.x;
    __shared__ float ps[8];
    __shared__ int   id8[8];

    if (tid < 8) {
        const long long t = (long long)blk*8 + tid;
        const float ns = na_part[((long long)blk*2 + 0)*8 + tid]
                       + na_part[((long long)blk*2 + 1)*8 + tid];
        ps[tid] = ns * npp[t];
        id8[tid] = idx[t];
    }
    __syncthreads();
    if (tid == 0) {
        float l1 = 0.f;
        #pragma unroll
        for (int r = 0; r < 8; ++r) l1 += fabsf(ps[r]);
        l1 = fmaxf(l1, 1e-12f);
        #pragma unroll
        for (int r = 0; r < 8; ++r) ps[r] /= l1;
    }
    __syncthreads();

    float acc = 0.f;
    #pragma unroll
    for (int r = 0; r < 8; ++r) acc += E[(long long)id8[r]*D + tid] * ps[r];
    out[OUT_SCORED + (long long)blk*D + tid] = acc * 16.f;  /* sqrt(D)=16 */

    if (tid < 8) out[OUT_PS + (long long)blk*8 + tid] = ps[tid];
}

extern "C" void kernel_launch(void* const* d_in, const int* in_sizes, int n_in,
                              void* d_out, int out_size, void* d_ws, size_t ws_size,
                              hipStream_t stream)
{
    const float* na_pred = (const float*)d_in[2];
    const float* emb     = (const float*)d_in[3];
    const float* Wq      = (const float*)d_in[4];
    const float* bq      = (const float*)d_in[5];
    const float* Wk      = (const float*)d_in[6];
    const float* bk      = (const float*)d_in[7];

    char* ws = (char*)d_ws;
    int*   ws_idx  = (int*)  (ws + OFF_IDX);
    float* ws_npp  = (float*)(ws + OFF_NPP);
    float* ws_M    = (float*)(ws + OFF_M);
    float* ws_u    = (float*)(ws + OFF_U);
    float* ws_w    = (float*)(ws + OFF_W);
    float* ws_P    = (float*)(ws + OFF_P);
    float* ws_np   = (float*)(ws + OFF_NPART);
    float* out     = (float*)d_out;

    topk_kernel<<<ROWS, 256, 0, stream>>>(na_pred, ws_idx, ws_npp, out + OUT_IDX);
    m_kernel<<<D, 256, 0, stream>>>(Wq, Wk, ws_M);
    bias_kernel<<<1, 256, 0, stream>>>(Wq, Wk, bq, bk, ws_u, ws_w);
    p_kernel<<<(VOCAB + 15)/16, 256, 0, stream>>>(emb, ws_M, ws_P);
    hipMemsetAsync(ws_np, 0, BSZ*SEQ*2*8*sizeof(float), stream);
    attn_kernel<<<ROWS, 128, 0, stream>>>(ws_P, emb, ws_idx, ws_w, ws_np);
    finalize_kernel<<<ROWS, 256, 0, stream>>>(emb, ws_idx, ws_npp, ws_np, out);
}

// Round 2
// 191.099 us; speedup vs baseline: 1.7173x; 1.7173x over previous
//
#include <hip/hip_runtime.h>
#include <math.h>

#define TOPK 8
#define D    256
#define VOCAB 5000
#define BSZ  64
#define SEQ  128
#define ROWS (BSZ*SEQ)

/* workspace layout (bytes) */
#define OFF_IDX   0          /* int32  ROWS*8 */
#define OFF_NPP   262144     /* f32    ROWS*8 */
#define OFF_M     524288     /* f32    256*256 */
#define OFF_W     787456     /* f32    256 */
#define OFF_P     790528     /* f32    5000*256 */
#define OFF_NPART 5910528    /* f32    BSZ*SEQ*2*8 */
#define OFF_KBV   6434816    /* f32    5000 */

/* d_out layout (floats) */
#define OUT_SCORED 0
#define OUT_PS     2097152
#define OUT_IDX    2162688

typedef unsigned long long u64;
typedef unsigned int u32;

/* ============ kernel 1: online softmax stats + register top-8 ============ */
__global__ __launch_bounds__(256) void topk_kernel(
    const float* __restrict__ na_pred,
    int*  __restrict__ out_idx,
    float* __restrict__ out_npp,
    float* __restrict__ out_idx_f)
{
    __shared__ u64   wavetop[32];     /* 4 waves x 8 */
    __shared__ float wm[4], wsum[4];

    const int tid  = threadIdx.x;
    const int wid  = tid >> 6, lane = tid & 63;
    const long long base = (long long)blockIdx.x * VOCAB;
    const float4* src = (const float4*)(na_pred + base);

    u64 a[8];
    #pragma unroll
    for (int r = 0; r < 8; ++r) a[r] = 0ULL;
    float m = -INFINITY, ssum = 0.f;

    for (int i4 = tid; i4 < VOCAB/4; i4 += 256) {
        const float4 v = src[i4];
        const float vv[4] = {v.x, v.y, v.z, v.w};
        #pragma unroll
        for (int c = 0; c < 4; ++c) {
            const float x = vv[c];
            const float mn = fmaxf(m, x);
            ssum = ssum * __expf(m - mn) + __expf(x - mn);
            m = mn;
            u32 bu = __float_as_uint(x);
            u32 key = bu ^ ((u32)((int)bu >> 31) | 0x80000000u);
            u64 k64 = ((u64)key << 32) | (u64)(0xFFFFFFFFu - (u32)(4*i4 + c));
            if (k64 > a[7]) {
                #pragma unroll
                for (int r = 7; r >= 1; --r)
                    a[r] = (k64 > a[r-1]) ? a[r-1] : ((k64 > a[r]) ? k64 : a[r]);
                a[0] = (k64 > a[0]) ? k64 : a[0];
            }
        }
    }

    /* wave-reduce online stats */
    #pragma unroll
    for (int st = 1; st < 64; st <<= 1) {
        const float om = __shfl_xor(m, st, 64);
        const float os = __shfl_xor(ssum, st, 64);
        const float mn = fmaxf(m, om);
        ssum = ssum * __expf(m - mn) + os * __expf(om - mn);
        m = mn;
    }
    if (lane == 0) { wm[wid] = m; wsum[wid] = ssum; }

    /* wave-merge top-8: 8 rounds of wave argmax over register arrays */
    #pragma unroll
    for (int r = 0; r < 8; ++r) {
        u64 mm = a[0];
        #pragma unroll
        for (int j = 1; j < 8; ++j) mm = (a[j] > mm) ? a[j] : mm;
        #pragma unroll
        for (int st = 1; st < 64; st <<= 1) {
            const u64 o = __shfl_xor(mm, st, 64);
            mm = (o > mm) ? o : mm;
        }
        #pragma unroll
        for (int j = 0; j < 8; ++j) if (a[j] == mm) a[j] = 0ULL;
        if (lane == 0) wavetop[wid*8 + r] = mm;
    }
    __syncthreads();

    /* final merge in wave 0 over 32 candidates */
    if (wid == 0) {
        u64 c = (lane < 32) ? wavetop[lane] : 0ULL;
        u64 res[8];
        #pragma unroll
        for (int r = 0; r < 8; ++r) {
            u64 mm = c;
            #pragma unroll
            for (int st = 1; st < 64; st <<= 1) {
                const u64 o = __shfl_xor(mm, st, 64);
                mm = (o > mm) ? o : mm;
            }
            if (c == mm) c = 0ULL;
            res[r] = mm;
        }
        if (lane == 0) {
            float M0 = fmaxf(fmaxf(wm[0], wm[1]), fmaxf(wm[2], wm[3]));
            float S0 = wsum[0]*__expf(wm[0]-M0) + wsum[1]*__expf(wm[1]-M0)
                     + wsum[2]*__expf(wm[2]-M0) + wsum[3]*__expf(wm[3]-M0);
            float p[8]; int ix[8]; float pm = -INFINITY;
            #pragma unroll
            for (int r = 0; r < 8; ++r) {
                const u32 key = (u32)(res[r] >> 32);
                ix[r] = (int)(0xFFFFFFFFu - (u32)(res[r] & 0xFFFFFFFFu));
                const u32 bu = key ^ ((key & 0x80000000u) ? 0x80000000u : 0xFFFFFFFFu);
                p[r] = __expf(__uint_as_float(bu) - M0) / S0;
                pm = fmaxf(pm, p[r]);
            }
            float q[8], s2 = 0.f;
            #pragma unroll
            for (int r = 0; r < 8; ++r) { q[r] = __expf(p[r] - pm); s2 += q[r]; }
            const long long ob = (long long)blockIdx.x * TOPK;
            #pragma unroll
            for (int r = 0; r < 8; ++r) {
                out_idx[ob + r]   = ix[r];
                out_npp[ob + r]   = q[r] / s2;
                out_idx_f[ob + r] = (float)ix[r];
            }
        }
    }
}

/* ============ kernel 2: M = Wq @ Wk^T ============ */
__global__ __launch_bounds__(256) void m_kernel(
    const float* __restrict__ Wq, const float* __restrict__ Wk,
    float* __restrict__ M)
{
    __shared__ float qrow[D];
    const int a = blockIdx.x, j = threadIdx.x;
    qrow[j] = Wq[a*D + j];
    __syncthreads();
    float acc = 0.f;
    #pragma unroll 4
    for (int d4 = 0; d4 < 64; ++d4) {
        const float4 wk = *(const float4*)&Wk[j*D + 4*d4];
        const float4 q4 = *(const float4*)&qrow[4*d4];
        acc += wk.x*q4.x + wk.y*q4.y + wk.z*q4.z + wk.w*q4.w;
    }
    M[a*D + j] = acc;
}

/* ============ kernel 2b: w = Wk @ bq ============ */
__global__ __launch_bounds__(256) void bias_kernel(
    const float* __restrict__ Wk, const float* __restrict__ bq,
    float* __restrict__ w)
{
    const int i = threadIdx.x;
    float aw = 0.f;
    #pragma unroll 4
    for (int d4 = 0; d4 < 64; ++d4) {
        const float4 wk = *(const float4*)&Wk[i*D + 4*d4];
        const float4 b4 = *(const float4*)&bq[4*d4];
        aw += wk.x*b4.x + wk.y*b4.y + wk.z*b4.z + wk.w*b4.w;
    }
    w[i] = aw;
}

/* ============ kernel 2c: kbv[v] = E[v] . w  (one wave per row) ============ */
__global__ __launch_bounds__(256) void kbv_kernel(
    const float* __restrict__ E, const float* __restrict__ w,
    float* __restrict__ kbv)
{
    const int row  = blockIdx.x * 4 + (threadIdx.x >> 6);
    const int lane = threadIdx.x & 63;
    if (row >= VOCAB) return;
    const float4 e  = *(const float4*)&E[(long long)row*D + 4*lane];
    const float4 ww = *(const float4*)&w[4*lane];
    float p = e.x*ww.x + e.y*ww.y + e.z*ww.z + e.w*ww.w;
    #pragma unroll
    for (int st = 1; st < 64; st <<= 1) p += __shfl_xor(p, st, 64);
    if (lane == 0) kbv[row] = p;
}

/* ============ kernel 3: P = E @ M (16 rows/block, 4x4 reg tile) ============ */
__global__ __launch_bounds__(256) void p_kernel(
    const float* __restrict__ E, const float* __restrict__ M,
    float* __restrict__ P)
{
    __shared__ float seT[256][20];   /* transposed E tile, padded: conflict-free */
    const int tid = threadIdx.x;
    const int r0  = blockIdx.x * 16;
    {
        const int r = tid >> 4, d4b = tid & 15;
        const bool ok = (r0 + r) < VOCAB;
        #pragma unroll
        for (int k = 0; k < 4; ++k) {
            const int d4 = d4b + 16*k;
            float4 v = make_float4(0.f, 0.f, 0.f, 0.f);
            if (ok) v = *(const float4*)&E[(long long)(r0+r)*D + 4*d4];
            seT[4*d4+0][r] = v.x; seT[4*d4+1][r] = v.y;
            seT[4*d4+2][r] = v.z; seT[4*d4+3][r] = v.w;
        }
    }
    __syncthreads();
    const int rg = tid >> 6, j4 = tid & 63;
    float acc[4][4];
    #pragma unroll
    for (int i = 0; i < 4; ++i)
        { acc[i][0]=0.f; acc[i][1]=0.f; acc[i][2]=0.f; acc[i][3]=0.f; }
    #pragma unroll 4
    for (int d = 0; d < 256; ++d) {
        const float4 m4 = *(const float4*)&M[d*D + 4*j4];
        const float4 s4 = *(const float4*)&seT[d][4*rg];
        const float ss[4] = {s4.x, s4.y, s4.z, s4.w};
        #pragma unroll
        for (int rr = 0; rr < 4; ++rr) {
            acc[rr][0] += ss[rr]*m4.x; acc[rr][1] += ss[rr]*m4.y;
            acc[rr][2] += ss[rr]*m4.z; acc[rr][3] += ss[rr]*m4.w;
        }
    }
    #pragma unroll
    for (int rr = 0; rr < 4; ++rr) {
        const int row = r0 + 4*rg + rr;
        if (row < VOCAB) {
            float4 o;
            o.x = acc[rr][0]; o.y = acc[rr][1]; o.z = acc[rr][2]; o.w = acc[rr][3];
            *(float4*)&P[(long long)row*D + 4*j4] = o;
        }
    }
}

/* ============ kernel 4: masked block attention (1 wave / chunk) ============ */
__global__ __launch_bounds__(64) void attn_kernel(
    const float* __restrict__ P, const float* __restrict__ E,
    const int*  __restrict__ idx, const float* __restrict__ kbv,
    float* __restrict__ na_part /* (BSZ,SEQ,2,8) */)
{
    const int blk = blockIdx.x;
    const int b = blk >> 7, s = blk & 127;
    const int tid = threadIdx.x;

    __shared__ float Ps[8][260];
    __shared__ float Es[16][260];
    __shared__ int   qidx[8];
    __shared__ int   kidx[16];
    __shared__ float kb[16];
    __shared__ int   kchs[2];

    int kcl[2]; int nk = 0;
    if (s > 0)       kcl[nk++] = s - 1;
    if (s < SEQ - 1) kcl[nk++] = s + 1;
    const int nkeys = nk * 8;

    if (tid < 2 && tid < nk) kchs[tid] = kcl[tid];
    if (tid < 8) qidx[tid] = idx[blk*8 + tid];
    if (tid < 16) {
        if (tid < nkeys) {
            const int v = idx[(b*SEQ + kcl[tid >> 3])*8 + (tid & 7)];
            kidx[tid] = v;
            kb[tid]   = kbv[v];
        } else { kidx[tid] = 0; kb[tid] = 0.f; }
    }
    __syncthreads();

    /* stage: P rows (queries, f32) + E rows (keys, f32), float4 */
    #pragma unroll
    for (int r = 0; r < 8; ++r)
        *(float4*)&Ps[r][4*tid] = *(const float4*)&P[(long long)qidx[r]*D + 4*tid];
    for (int r = 0; r < 16; ++r)
        if (r < nkeys)
            *(float4*)&Es[r][4*tid] = *(const float4*)&E[(long long)kidx[r]*D + 4*tid];
    __syncthreads();

    /* scores: lane = (qp, ki); queries qp and qp+4 */
    const int qp = tid >> 4, ki = tid & 15;
    float acc0 = 0.f, acc1 = 0.f;
    const float* pr0 = Ps[qp];
    const float* pr1 = Ps[qp + 4];
    const float* er  = Es[ki];
    #pragma unroll 4
    for (int d4 = 0; d4 < 64; ++d4) {
        const float4 e  = *(const float4*)&er[4*d4];
        const float4 p0 = *(const float4*)&pr0[4*d4];
        const float4 p1 = *(const float4*)&pr1[4*d4];
        acc0 += p0.x*e.x + p0.y*e.y + p0.z*e.z + p0.w*e.w;
        acc1 += p1.x*e.x + p1.y*e.y + p1.z*e.z + p1.w*e.w;
    }
    const bool kvalid = ki < nkeys;
    const float s0 = kvalid ? (16.f*acc0 + kb[ki]) : -1e30f;
    const float s1 = kvalid ? (16.f*acc1 + kb[ki]) : -1e30f;

    /* softmax across the 16 lanes of each qp group */
    float m0 = s0, m1 = s1;
    #pragma unroll
    for (int st = 1; st < 16; st <<= 1) {
        m0 = fmaxf(m0, __shfl_xor(m0, st, 64));
        m1 = fmaxf(m1, __shfl_xor(m1, st, 64));
    }
    float e0 = kvalid ? __expf(s0 - m0) : 0.f;
    float e1 = kvalid ? __expf(s1 - m1) : 0.f;
    float t0 = e0, t1 = e1;
    #pragma unroll
    for (int st = 1; st < 16; st <<= 1) {
        t0 += __shfl_xor(t0, st, 64);
        t1 += __shfl_xor(t1, st, 64);
    }
    const float a0 = e0 / t0, a1 = e1 / t1;

    /* column sums over the 8 queries: lanes {ki+16q} */
    float cs = a0 + a1;
    cs += __shfl_xor(cs, 16, 64);
    cs += __shfl_xor(cs, 32, 64);
    if (tid < 16 && kvalid) {
        const int kc   = kchs[tid >> 3];
        const int slot = (kc == s + 1) ? 0 : 1;
        na_part[((b*SEQ + kc)*2 + slot)*8 + (tid & 7)] = cs;
    }
}

/* ============ kernel 5: finalize ============ */
__global__ __launch_bounds__(256) void finalize_kernel(
    const float* __restrict__ E, const int* __restrict__ idx,
    const float* __restrict__ npp, const float* __restrict__ na_part,
    float* __restrict__ out)
{
    const int blk = blockIdx.x;
    const int tid = threadIdx.x;
    __shared__ float ps[8];
    __shared__ int   id8[8];

    if (tid < 8) {
        const long long t = (long long)blk*8 + tid;
        const float ns = na_part[((long long)blk*2 + 0)*8 + tid]
                       + na_part[((long long)blk*2 + 1)*8 + tid];
        ps[tid] = ns * npp[t];
        id8[tid] = idx[t];
    }
    __syncthreads();
    if (tid == 0) {
        float l1 = 0.f;
        #pragma unroll
        for (int r = 0; r < 8; ++r) l1 += fabsf(ps[r]);
        l1 = fmaxf(l1, 1e-12f);
        #pragma unroll
        for (int r = 0; r < 8; ++r) ps[r] /= l1;
    }
    __syncthreads();

    float acc = 0.f;
    #pragma unroll
    for (int r = 0; r < 8; ++r) acc += E[(long long)id8[r]*D + tid] * ps[r];
    out[OUT_SCORED + (long long)blk*D + tid] = acc * 16.f;
    if (tid < 8) out[OUT_PS + (long long)blk*8 + tid] = ps[tid];
}

extern "C" void kernel_launch(void* const* d_in, const int* in_sizes, int n_in,
                              void* d_out, int out_size, void* d_ws, size_t ws_size,
                              hipStream_t stream)
{
    const float* na_pred = (const float*)d_in[2];
    const float* emb     = (const float*)d_in[3];
    const float* Wq      = (const float*)d_in[4];
    const float* bq      = (const float*)d_in[5];
    const float* Wk      = (const float*)d_in[6];
    const float* bk      = (const float*)d_in[7];
    (void)bk;

    char* ws = (char*)d_ws;
    int*   ws_idx = (int*)  (ws + OFF_IDX);
    float* ws_npp = (float*)(ws + OFF_NPP);
    float* ws_M   = (float*)(ws + OFF_M);
    float* ws_w   = (float*)(ws + OFF_W);
    float* ws_P   = (float*)(ws + OFF_P);
    float* ws_np  = (float*)(ws + OFF_NPART);
    float* ws_kbv = (float*)(ws + OFF_KBV);
    float* out    = (float*)d_out;

    topk_kernel<<<ROWS, 256, 0, stream>>>(na_pred, ws_idx, ws_npp, out + OUT_IDX);
    m_kernel<<<D, 256, 0, stream>>>(Wq, Wk, ws_M);
    bias_kernel<<<1, 256, 0, stream>>>(Wk, bq, ws_w);
    kbv_kernel<<<(VOCAB + 3)/4, 256, 0, stream>>>(emb, ws_w, ws_kbv);
    p_kernel<<<(VOCAB + 15)/16, 256, 0, stream>>>(emb, ws_M, ws_P);
    hipMemsetAsync(ws_np, 0, BSZ*SEQ*2*8*sizeof(float), stream);
    attn_kernel<<<ROWS, 64, 0, stream>>>(ws_P, emb, ws_idx, ws_kbv, ws_np);
    finalize_kernel<<<ROWS, 256, 0, stream>>>(emb, ws_idx, ws_npp, ws_np, out);
}

// Round 3
// 159.344 us; speedup vs baseline: 2.0596x; 1.1993x over previous
//
#include <hip/hip_runtime.h>
#include <math.h>

#define TOPK 8
#define D    256
#define VOCAB 5000
#define BSZ  64
#define SEQ  128
#define ROWS (BSZ*SEQ)
#define NF4  (VOCAB/4)      /* 1250 float4 per row */

/* workspace layout (bytes) */
#define OFF_IDX   0          /* int32  ROWS*8 */
#define OFF_NPP   262144     /* f32    ROWS*8 */
#define OFF_M     524288     /* f32    256*256 */
#define OFF_W     787456     /* f32    256 */
#define OFF_P     790528     /* f32    5000*256 */
#define OFF_NPART 5910528    /* f32    BSZ*SEQ*2*8 */
#define OFF_KBV   6434816    /* f32    5000 */

/* d_out layout (floats) */
#define OUT_SCORED 0
#define OUT_PS     2097152
#define OUT_IDX    2162688

typedef unsigned long long u64;
typedef unsigned int u32;

__device__ __forceinline__ float wave_fmax(float v) {
    #pragma unroll
    for (int st = 1; st < 64; st <<= 1) v = fmaxf(v, __shfl_xor(v, st, 64));
    return v;
}
__device__ __forceinline__ float wave_fsum(float v) {
    #pragma unroll
    for (int st = 1; st < 64; st <<= 1) v += __shfl_xor(v, st, 64);
    return v;
}
__device__ __forceinline__ u64 wave_umax(u64 v) {
    #pragma unroll
    for (int st = 1; st < 64; st <<= 1) {
        const u64 o = __shfl_xor(v, st, 64);
        v = (o > v) ? o : v;
    }
    return v;
}
__device__ __forceinline__ u64 pack_key(float x, int idx) {
    u32 bu = __float_as_uint(x);
    u32 key = bu ^ ((u32)((int)bu >> 31) | 0x80000000u);
    return ((u64)key << 32) | (u64)(0xFFFFFFFFu ^ (u32)idx);
}

/* ============ kernel 1: one row per wave, threshold-filtered top-8 ============ */
__global__ __launch_bounds__(256) void topk_kernel(
    const float* __restrict__ na_pred,
    int*  __restrict__ out_idx,
    float* __restrict__ out_npp,
    float* __restrict__ out_idx_f)
{
    __shared__ float cv[4][64];
    __shared__ int   ci[4][64];
    __shared__ int   cnt[4];

    const int tid  = threadIdx.x;
    const int w    = tid >> 6, lane = tid & 63;
    const int row  = blockIdx.x * 4 + w;
    const float4* src = (const float4*)(na_pred + (long long)row * VOCAB);

    /* ---- P1: per-lane max ---- */
    float lmax = -INFINITY;
    #pragma unroll
    for (int it = 0; it < 20; ++it) {
        const int i4 = lane + 64*it;
        if (i4 < NF4) {
            const float4 v = src[i4];
            lmax = fmaxf(lmax, fmaxf(fmaxf(v.x, v.y), fmaxf(v.z, v.w)));
        }
    }
    const float rowmax = wave_fmax(lmax);

    /* threshold = 8th largest distinct lane-max (lower bound on true 8th value) */
    float am = lmax, thr = rowmax;
    #pragma unroll
    for (int r = 0; r < 8; ++r) {
        const float cur = wave_fmax(am);
        if (am == cur) am = -INFINITY;
        thr = cur;
    }

    if (lane == 0) cnt[w] = 0;
    __syncthreads();

    /* ---- P2: sumexp + candidate compaction ---- */
    float se = 0.f;
    #pragma unroll
    for (int it = 0; it < 20; ++it) {
        const int i4 = lane + 64*it;
        if (i4 < NF4) {
            const float4 v = src[i4];
            const float vv[4] = {v.x, v.y, v.z, v.w};
            #pragma unroll
            for (int c = 0; c < 4; ++c) {
                const float x = vv[c];
                se += __expf(x - rowmax);
                if (x >= thr) {
                    const int pos = atomicAdd(&cnt[w], 1);
                    if (pos < 64) { cv[w][pos] = x; ci[w][pos] = 4*i4 + c; }
                }
            }
        }
    }
    const float S = wave_fsum(se);
    __syncthreads();

    const int cntv = cnt[w];
    u64 res[8];
    if (cntv <= 64) {
        /* fast path: one candidate per lane, 8 rounds of wave argmax */
        u64 key = 0ULL;
        if (lane < cntv) key = pack_key(cv[w][lane], ci[w][lane]);
        #pragma unroll
        for (int r = 0; r < 8; ++r) {
            const u64 mm = wave_umax(key);
            if (key == mm) key = 0ULL;
            res[r] = mm;
        }
    } else {
        /* exact fallback (ties flooded the filter): repeated selection over row */
        u64 last = ~0ULL;
        for (int r = 0; r < 8; ++r) {
            u64 best = 0ULL;
            for (int it = 0; it < 20; ++it) {
                const int i4 = lane + 64*it;
                if (i4 < NF4) {
                    const float4 v = src[i4];
                    const float vv[4] = {v.x, v.y, v.z, v.w};
                    #pragma unroll
                    for (int c = 0; c < 4; ++c) {
                        const u64 k = pack_key(vv[c], 4*i4 + c);
                        if (k < last && k > best) best = k;
                    }
                }
            }
            best = wave_umax(best);
            res[r] = best; last = best;
        }
    }

    if (lane == 0) {
        float p[8]; int ix[8]; float pm = -INFINITY;
        #pragma unroll
        for (int r = 0; r < 8; ++r) {
            const u32 key = (u32)(res[r] >> 32);
            ix[r] = (int)(0xFFFFFFFFu ^ (u32)(res[r] & 0xFFFFFFFFu));
            const u32 bu = key ^ ((key & 0x80000000u) ? 0x80000000u : 0xFFFFFFFFu);
            p[r] = __expf(__uint_as_float(bu) - rowmax) / S;
            pm = fmaxf(pm, p[r]);
        }
        float q[8], s2 = 0.f;
        #pragma unroll
        for (int r = 0; r < 8; ++r) { q[r] = __expf(p[r] - pm); s2 += q[r]; }
        const long long ob = (long long)row * TOPK;
        #pragma unroll
        for (int r = 0; r < 8; ++r) {
            out_idx[ob + r]   = ix[r];
            out_npp[ob + r]   = q[r] / s2;
            out_idx_f[ob + r] = (float)ix[r];
        }
    }
}

/* ============ kernel 2: M = Wq @ Wk^T ============ */
__global__ __launch_bounds__(256) void m_kernel(
    const float* __restrict__ Wq, const float* __restrict__ Wk,
    float* __restrict__ M)
{
    __shared__ float qrow[D];
    const int a = blockIdx.x, j = threadIdx.x;
    qrow[j] = Wq[a*D + j];
    __syncthreads();
    float acc = 0.f;
    #pragma unroll 4
    for (int d4 = 0; d4 < 64; ++d4) {
        const float4 wk = *(const float4*)&Wk[j*D + 4*d4];
        const float4 q4 = *(const float4*)&qrow[4*d4];
        acc += wk.x*q4.x + wk.y*q4.y + wk.z*q4.z + wk.w*q4.w;
    }
    M[a*D + j] = acc;
}

/* ============ kernel 2b: w = Wk @ bq ============ */
__global__ __launch_bounds__(256) void bias_kernel(
    const float* __restrict__ Wk, const float* __restrict__ bq,
    float* __restrict__ w)
{
    const int i = threadIdx.x;
    float aw = 0.f;
    #pragma unroll 4
    for (int d4 = 0; d4 < 64; ++d4) {
        const float4 wk = *(const float4*)&Wk[i*D + 4*d4];
        const float4 b4 = *(const float4*)&bq[4*d4];
        aw += wk.x*b4.x + wk.y*b4.y + wk.z*b4.z + wk.w*b4.w;
    }
    w[i] = aw;
}

/* ============ kernel 2c: kbv[v] = E[v] . w ============ */
__global__ __launch_bounds__(256) void kbv_kernel(
    const float* __restrict__ E, const float* __restrict__ w,
    float* __restrict__ kbv)
{
    const int row  = blockIdx.x * 4 + (threadIdx.x >> 6);
    const int lane = threadIdx.x & 63;
    if (row >= VOCAB) return;
    const float4 e  = *(const float4*)&E[(long long)row*D + 4*lane];
    const float4 ww = *(const float4*)&w[4*lane];
    float p = e.x*ww.x + e.y*ww.y + e.z*ww.z + e.w*ww.w;
    #pragma unroll
    for (int st = 1; st < 64; st <<= 1) p += __shfl_xor(p, st, 64);
    if (lane == 0) kbv[row] = p;
}

/* ============ kernel 3: P = E @ M (16 rows/block, 4x4 reg tile) ============ */
__global__ __launch_bounds__(256) void p_kernel(
    const float* __restrict__ E, const float* __restrict__ M,
    float* __restrict__ P)
{
    __shared__ float seT[256][20];
    const int tid = threadIdx.x;
    const int r0  = blockIdx.x * 16;
    {
        const int r = tid >> 4, d4b = tid & 15;
        const bool ok = (r0 + r) < VOCAB;
        #pragma unroll
        for (int k = 0; k < 4; ++k) {
            const int d4 = d4b + 16*k;
            float4 v = make_float4(0.f, 0.f, 0.f, 0.f);
            if (ok) v = *(const float4*)&E[(long long)(r0+r)*D + 4*d4];
            seT[4*d4+0][r] = v.x; seT[4*d4+1][r] = v.y;
            seT[4*d4+2][r] = v.z; seT[4*d4+3][r] = v.w;
        }
    }
    __syncthreads();
    const int rg = tid >> 6, j4 = tid & 63;
    float acc[4][4];
    #pragma unroll
    for (int i = 0; i < 4; ++i)
        { acc[i][0]=0.f; acc[i][1]=0.f; acc[i][2]=0.f; acc[i][3]=0.f; }
    #pragma unroll 4
    for (int d = 0; d < 256; ++d) {
        const float4 m4 = *(const float4*)&M[d*D + 4*j4];
        const float4 s4 = *(const float4*)&seT[d][4*rg];
        const float ss[4] = {s4.x, s4.y, s4.z, s4.w};
        #pragma unroll
        for (int rr = 0; rr < 4; ++rr) {
            acc[rr][0] += ss[rr]*m4.x; acc[rr][1] += ss[rr]*m4.y;
            acc[rr][2] += ss[rr]*m4.z; acc[rr][3] += ss[rr]*m4.w;
        }
    }
    #pragma unroll
    for (int rr = 0; rr < 4; ++rr) {
        const int row = r0 + 4*rg + rr;
        if (row < VOCAB) {
            float4 o;
            o.x = acc[rr][0]; o.y = acc[rr][1]; o.z = acc[rr][2]; o.w = acc[rr][3];
            *(float4*)&P[(long long)row*D + 4*j4] = o;
        }
    }
}

/* ============ kernel 4: masked block attention (1 wave / chunk) ============ */
__global__ __launch_bounds__(64) void attn_kernel(
    const float* __restrict__ P, const float* __restrict__ E,
    const int*  __restrict__ idx, const float* __restrict__ kbv,
    float* __restrict__ na_part /* (BSZ,SEQ,2,8) */)
{
    const int blk = blockIdx.x;
    const int b = blk >> 7, s = blk & 127;
    const int tid = threadIdx.x;

    __shared__ float Ps[8][260];
    __shared__ float Es[16][260];
    __shared__ int   qidx[8];
    __shared__ int   kidx[16];
    __shared__ float kb[16];
    __shared__ int   kchs[2];

    int kcl[2]; int nk = 0;
    if (s > 0)       kcl[nk++] = s - 1;
    if (s < SEQ - 1) kcl[nk++] = s + 1;
    const int nkeys = nk * 8;

    if (tid < 2 && tid < nk) kchs[tid] = kcl[tid];
    if (tid < 8) qidx[tid] = idx[blk*8 + tid];
    if (tid < 16) {
        if (tid < nkeys) {
            const int v = idx[(b*SEQ + kcl[tid >> 3])*8 + (tid & 7)];
            kidx[tid] = v;
            kb[tid]   = kbv[v];
        } else { kidx[tid] = 0; kb[tid] = 0.f; }
    }
    __syncthreads();

    #pragma unroll
    for (int r = 0; r < 8; ++r)
        *(float4*)&Ps[r][4*tid] = *(const float4*)&P[(long long)qidx[r]*D + 4*tid];
    for (int r = 0; r < 16; ++r)
        if (r < nkeys)
            *(float4*)&Es[r][4*tid] = *(const float4*)&E[(long long)kidx[r]*D + 4*tid];
    __syncthreads();

    const int qp = tid >> 4, ki = tid & 15;
    float acc0 = 0.f, acc1 = 0.f;
    const float* pr0 = Ps[qp];
    const float* pr1 = Ps[qp + 4];
    const float* er  = Es[ki];
    #pragma unroll 4
    for (int d4 = 0; d4 < 64; ++d4) {
        const float4 e  = *(const float4*)&er[4*d4];
        const float4 p0 = *(const float4*)&pr0[4*d4];
        const float4 p1 = *(const float4*)&pr1[4*d4];
        acc0 += p0.x*e.x + p0.y*e.y + p0.z*e.z + p0.w*e.w;
        acc1 += p1.x*e.x + p1.y*e.y + p1.z*e.z + p1.w*e.w;
    }
    const bool kvalid = ki < nkeys;
    const float s0 = kvalid ? (16.f*acc0 + kb[ki]) : -1e30f;
    const float s1 = kvalid ? (16.f*acc1 + kb[ki]) : -1e30f;

    float m0 = s0, m1 = s1;
    #pragma unroll
    for (int st = 1; st < 16; st <<= 1) {
        m0 = fmaxf(m0, __shfl_xor(m0, st, 64));
        m1 = fmaxf(m1, __shfl_xor(m1, st, 64));
    }
    float e0 = kvalid ? __expf(s0 - m0) : 0.f;
    float e1 = kvalid ? __expf(s1 - m1) : 0.f;
    float t0 = e0, t1 = e1;
    #pragma unroll
    for (int st = 1; st < 16; st <<= 1) {
        t0 += __shfl_xor(t0, st, 64);
        t1 += __shfl_xor(t1, st, 64);
    }
    const float a0 = e0 / t0, a1 = e1 / t1;

    float cs = a0 + a1;
    cs += __shfl_xor(cs, 16, 64);
    cs += __shfl_xor(cs, 32, 64);
    if (tid < 16 && kvalid) {
        const int kc   = kchs[tid >> 3];
        const int slot = (kc == s + 1) ? 0 : 1;
        na_part[((b*SEQ + kc)*2 + slot)*8 + (tid & 7)] = cs;
    }
}

/* ============ kernel 5: finalize ============ */
__global__ __launch_bounds__(256) void finalize_kernel(
    const float* __restrict__ E, const int* __restrict__ idx,
    const float* __restrict__ npp, const float* __restrict__ na_part,
    float* __restrict__ out)
{
    const int blk = blockIdx.x;
    const int tid = threadIdx.x;
    __shared__ float ps[8];
    __shared__ int   id8[8];

    if (tid < 8) {
        const long long t = (long long)blk*8 + tid;
        const float ns = na_part[((long long)blk*2 + 0)*8 + tid]
                       + na_part[((long long)blk*2 + 1)*8 + tid];
        ps[tid] = ns * npp[t];
        id8[tid] = idx[t];
    }
    __syncthreads();
    if (tid == 0) {
        float l1 = 0.f;
        #pragma unroll
        for (int r = 0; r < 8; ++r) l1 += fabsf(ps[r]);
        l1 = fmaxf(l1, 1e-12f);
        #pragma unroll
        for (int r = 0; r < 8; ++r) ps[r] /= l1;
    }
    __syncthreads();

    float acc = 0.f;
    #pragma unroll
    for (int r = 0; r < 8; ++r) acc += E[(long long)id8[r]*D + tid] * ps[r];
    out[OUT_SCORED + (long long)blk*D + tid] = acc * 16.f;
    if (tid < 8) out[OUT_PS + (long long)blk*8 + tid] = ps[tid];
}

extern "C" void kernel_launch(void* const* d_in, const int* in_sizes, int n_in,
                              void* d_out, int out_size, void* d_ws, size_t ws_size,
                              hipStream_t stream)
{
    const float* na_pred = (const float*)d_in[2];
    const float* emb     = (const float*)d_in[3];
    const float* Wq      = (const float*)d_in[4];
    const float* bq      = (const float*)d_in[5];
    const float* Wk      = (const float*)d_in[6];
    const float* bk      = (const float*)d_in[7];
    (void)bk;

    char* ws = (char*)d_ws;
    int*   ws_idx = (int*)  (ws + OFF_IDX);
    float* ws_npp = (float*)(ws + OFF_NPP);
    float* ws_M   = (float*)(ws + OFF_M);
    float* ws_w   = (float*)(ws + OFF_W);
    float* ws_P   = (float*)(ws + OFF_P);
    float* ws_np  = (float*)(ws + OFF_NPART);
    float* ws_kbv = (float*)(ws + OFF_KBV);
    float* out    = (float*)d_out;

    topk_kernel<<<ROWS/4, 256, 0, stream>>>(na_pred, ws_idx, ws_npp, out + OUT_IDX);
    m_kernel<<<D, 256, 0, stream>>>(Wq, Wk, ws_M);
    bias_kernel<<<1, 256, 0, stream>>>(Wk, bq, ws_w);
    kbv_kernel<<<(VOCAB + 3)/4, 256, 0, stream>>>(emb, ws_w, ws_kbv);
    p_kernel<<<(VOCAB + 15)/16, 256, 0, stream>>>(emb, ws_M, ws_P);
    hipMemsetAsync(ws_np, 0, BSZ*SEQ*2*8*sizeof(float), stream);
    attn_kernel<<<ROWS, 64, 0, stream>>>(ws_P, emb, ws_idx, ws_kbv, ws_np);
    finalize_kernel<<<ROWS, 256, 0, stream>>>(emb, ws_idx, ws_npp, ws_np, out);
}

// Round 4
// 153.075 us; speedup vs baseline: 2.1439x; 1.0410x over previous
//
#include <hip/hip_runtime.h>
#include <math.h>

#define TOPK 8
#define D    256
#define VOCAB 5000
#define BSZ  64
#define SEQ  128
#define ROWS (BSZ*SEQ)
#define NF4  (VOCAB/4)      /* 1250 float4 per row */
#define NF4P 1280           /* padded to 5120 floats */

/* workspace layout (bytes) */
#define OFF_IDX   0          /* int32  ROWS*8 */
#define OFF_NPP   262144     /* f32    ROWS*8 */
#define OFF_M     524288     /* f32    256*256 */
#define OFF_W     787456     /* f32    256 */
#define OFF_P     790528     /* f32    5000*256 */
#define OFF_NPART 5910528    /* f32    BSZ*SEQ*2*8 */
#define OFF_KBV   6434816    /* f32    5000 */

/* d_out layout (floats) */
#define OUT_SCORED 0
#define OUT_PS     2097152
#define OUT_IDX    2162688

typedef unsigned long long u64;
typedef unsigned int u32;

__device__ __forceinline__ float wave_fmax(float v) {
    #pragma unroll
    for (int st = 1; st < 64; st <<= 1) v = fmaxf(v, __shfl_xor(v, st, 64));
    return v;
}
__device__ __forceinline__ float wave_fsum(float v) {
    #pragma unroll
    for (int st = 1; st < 64; st <<= 1) v += __shfl_xor(v, st, 64);
    return v;
}
__device__ __forceinline__ u64 wave_umax(u64 v) {
    #pragma unroll
    for (int st = 1; st < 64; st <<= 1) {
        const u64 o = __shfl_xor(v, st, 64);
        v = (o > v) ? o : v;
    }
    return v;
}
__device__ __forceinline__ u64 pack_key(float x, int idx) {
    u32 bu = __float_as_uint(x);
    u32 key = bu ^ ((u32)((int)bu >> 31) | 0x80000000u);
    return ((u64)key << 32) | (u64)(0xFFFFFFFFu ^ (u32)idx);
}

/* ============ kernel 1: one row per block; fused stage+stats; filter ============ */
__global__ __launch_bounds__(256) void topk_kernel(
    const float* __restrict__ na_pred,
    int*  __restrict__ out_idx,
    float* __restrict__ out_npp,
    float* __restrict__ out_idx_f)
{
    __shared__ float row[NF4P*4];       /* 20480 B, padded with -INF */
    __shared__ float tmax[256];
    __shared__ float wsum[4];
    __shared__ float cv[64];
    __shared__ int   ci[64];
    __shared__ int   cnt;
    __shared__ float s_rowmax, s_thr;
    __shared__ u64   res_s[8];

    const int tid  = threadIdx.x;
    const int lane = tid & 63;
    const int wid  = tid >> 6;
    const long long base = (long long)blockIdx.x * VOCAB;
    const float4* src = (const float4*)(na_pred + base);

    if (tid == 0) cnt = 0;

    /* ---- fused stage + per-thread online (max, sumexp) ---- */
    float m = -INFINITY, se = 0.f;
    #pragma unroll
    for (int it = 0; it < 5; ++it) {
        const int i4 = tid + 256*it;
        float4 v = make_float4(-INFINITY, -INFINITY, -INFINITY, -INFINITY);
        if (i4 < NF4) {
            v = src[i4];
            const float vv[4] = {v.x, v.y, v.z, v.w};
            #pragma unroll
            for (int c = 0; c < 4; ++c) {
                const float x = vv[c];
                if (x > m) { se = se * __expf(m - x) + 1.f; m = x; }
                else       { se += __expf(x - m); }
            }
        }
        if (i4 < NF4P) ((float4*)row)[i4] = v;
    }
    tmax[tid] = m;
    __syncthreads();

    /* ---- wave 0: rowmax + threshold (8th largest of 64 combined maxes) ---- */
    if (tid < 64) {
        const float comb = fmaxf(fmaxf(tmax[tid], tmax[tid+64]),
                                 fmaxf(tmax[tid+128], tmax[tid+192]));
        const float rmax = wave_fmax(comb);
        float am = comb, t = rmax;
        #pragma unroll
        for (int r = 0; r < 8; ++r) {
            const float cur = wave_fmax(am);
            if (am == cur) am = -INFINITY;
            t = cur;
        }
        if (tid == 0) { s_rowmax = rmax; s_thr = t; }
    }
    __syncthreads();

    const float rowmax = s_rowmax, thr = s_thr;

    /* ---- block-sum of rescaled per-thread sumexp ---- */
    {
        const float c_t = se * __expf(m - rowmax);
        const float cw = wave_fsum(c_t);
        if (lane == 0) wsum[wid] = cw;
    }

    /* ---- candidate compaction from LDS (strided, conflict-free) ---- */
    #pragma unroll
    for (int it = 0; it < 20; ++it) {
        const float x = row[tid + 256*it];
        if (x >= thr) {
            const int pos = atomicAdd(&cnt, 1);
            if (pos < 64) { cv[pos] = x; ci[pos] = tid + 256*it; }
        }
    }
    __syncthreads();

    const int cntv = cnt;
    if (tid < 64) {
        if (cntv <= 64) {
            u64 key = 0ULL;
            if (tid < cntv) key = pack_key(cv[tid], ci[tid]);
            #pragma unroll
            for (int r = 0; r < 8; ++r) {
                const u64 mm = wave_umax(key);
                if (key == mm) key = 0ULL;
                if (tid == 0) res_s[r] = mm;
            }
        } else {
            /* exact fallback over LDS row (rare: tie floods) */
            u64 last = ~0ULL;
            for (int r = 0; r < 8; ++r) {
                u64 best = 0ULL;
                for (int j = 0; j < 80; ++j) {
                    const int i = tid + 64*j;
                    const u64 k = pack_key(row[i], i);
                    if (k < last && k > best) best = k;
                }
                best = wave_umax(best);
                if (tid == 0) res_s[r] = best;
                last = best;
            }
        }
    }
    __syncthreads();

    if (tid == 0) {
        const float S = wsum[0] + wsum[1] + wsum[2] + wsum[3];
        float p[8]; int ix[8]; float pm = -INFINITY;
        #pragma unroll
        for (int r = 0; r < 8; ++r) {
            const u64 res = res_s[r];
            const u32 key = (u32)(res >> 32);
            ix[r] = (int)(0xFFFFFFFFu ^ (u32)(res & 0xFFFFFFFFu));
            const u32 bu = key ^ ((key & 0x80000000u) ? 0x80000000u : 0xFFFFFFFFu);
            p[r] = __expf(__uint_as_float(bu) - rowmax) / S;
            pm = fmaxf(pm, p[r]);
        }
        float q[8], s2 = 0.f;
        #pragma unroll
        for (int r = 0; r < 8; ++r) { q[r] = __expf(p[r] - pm); s2 += q[r]; }
        const long long ob = (long long)blockIdx.x * TOPK;
        #pragma unroll
        for (int r = 0; r < 8; ++r) {
            out_idx[ob + r]   = ix[r];
            out_npp[ob + r]   = q[r] / s2;
            out_idx_f[ob + r] = (float)ix[r];
        }
    }
}

/* ============ kernel 2: M = Wq @ Wk^T ============ */
__global__ __launch_bounds__(256) void m_kernel(
    const float* __restrict__ Wq, const float* __restrict__ Wk,
    float* __restrict__ M)
{
    __shared__ float qrow[D];
    const int a = blockIdx.x, j = threadIdx.x;
    qrow[j] = Wq[a*D + j];
    __syncthreads();
    float acc = 0.f;
    #pragma unroll 4
    for (int d4 = 0; d4 < 64; ++d4) {
        const float4 wk = *(const float4*)&Wk[j*D + 4*d4];
        const float4 q4 = *(const float4*)&qrow[4*d4];
        acc += wk.x*q4.x + wk.y*q4.y + wk.z*q4.z + wk.w*q4.w;
    }
    M[a*D + j] = acc;
}

/* ============ kernel 2b: w = Wk @ bq ============ */
__global__ __launch_bounds__(256) void bias_kernel(
    const float* __restrict__ Wk, const float* __restrict__ bq,
    float* __restrict__ w)
{
    const int i = threadIdx.x;
    float aw = 0.f;
    #pragma unroll 4
    for (int d4 = 0; d4 < 64; ++d4) {
        const float4 wk = *(const float4*)&Wk[i*D + 4*d4];
        const float4 b4 = *(const float4*)&bq[4*d4];
        aw += wk.x*b4.x + wk.y*b4.y + wk.z*b4.z + wk.w*b4.w;
    }
    w[i] = aw;
}

/* ============ kernel 2c: kbv[v] = E[v] . w ============ */
__global__ __launch_bounds__(256) void kbv_kernel(
    const float* __restrict__ E, const float* __restrict__ w,
    float* __restrict__ kbv)
{
    const int row  = blockIdx.x * 4 + (threadIdx.x >> 6);
    const int lane = threadIdx.x & 63;
    if (row >= VOCAB) return;
    const float4 e  = *(const float4*)&E[(long long)row*D + 4*lane];
    const float4 ww = *(const float4*)&w[4*lane];
    float p = e.x*ww.x + e.y*ww.y + e.z*ww.z + e.w*ww.w;
    #pragma unroll
    for (int st = 1; st < 64; st <<= 1) p += __shfl_xor(p, st, 64);
    if (lane == 0) kbv[row] = p;
}

/* ============ kernel 3: P = E @ M (16 rows/block, 4x4 reg tile) ============ */
__global__ __launch_bounds__(256) void p_kernel(
    const float* __restrict__ E, const float* __restrict__ M,
    float* __restrict__ P)
{
    __shared__ float seT[256][20];
    const int tid = threadIdx.x;
    const int r0  = blockIdx.x * 16;
    {
        const int r = tid >> 4, d4b = tid & 15;
        const bool ok = (r0 + r) < VOCAB;
        #pragma unroll
        for (int k = 0; k < 4; ++k) {
            const int d4 = d4b + 16*k;
            float4 v = make_float4(0.f, 0.f, 0.f, 0.f);
            if (ok) v = *(const float4*)&E[(long long)(r0+r)*D + 4*d4];
            seT[4*d4+0][r] = v.x; seT[4*d4+1][r] = v.y;
            seT[4*d4+2][r] = v.z; seT[4*d4+3][r] = v.w;
        }
    }
    __syncthreads();
    const int rg = tid >> 6, j4 = tid & 63;
    float acc[4][4];
    #pragma unroll
    for (int i = 0; i < 4; ++i)
        { acc[i][0]=0.f; acc[i][1]=0.f; acc[i][2]=0.f; acc[i][3]=0.f; }
    #pragma unroll 4
    for (int d = 0; d < 256; ++d) {
        const float4 m4 = *(const float4*)&M[d*D + 4*j4];
        const float4 s4 = *(const float4*)&seT[d][4*rg];
        const float ss[4] = {s4.x, s4.y, s4.z, s4.w};
        #pragma unroll
        for (int rr = 0; rr < 4; ++rr) {
            acc[rr][0] += ss[rr]*m4.x; acc[rr][1] += ss[rr]*m4.y;
            acc[rr][2] += ss[rr]*m4.z; acc[rr][3] += ss[rr]*m4.w;
        }
    }
    #pragma unroll
    for (int rr = 0; rr < 4; ++rr) {
        const int row = r0 + 4*rg + rr;
        if (row < VOCAB) {
            float4 o;
            o.x = acc[rr][0]; o.y = acc[rr][1]; o.z = acc[rr][2]; o.w = acc[rr][3];
            *(float4*)&P[(long long)row*D + 4*j4] = o;
        }
    }
}

/* ============ kernel 4: masked block attention (1 wave / chunk) ============ */
__global__ __launch_bounds__(64) void attn_kernel(
    const float* __restrict__ P, const float* __restrict__ E,
    const int*  __restrict__ idx, const float* __restrict__ kbv,
    float* __restrict__ na_part /* (BSZ,SEQ,2,8) */)
{
    const int blk = blockIdx.x;
    const int b = blk >> 7, s = blk & 127;
    const int tid = threadIdx.x;

    __shared__ float Ps[8][260];
    __shared__ float Es[16][260];
    __shared__ int   qidx[8];
    __shared__ int   kidx[16];
    __shared__ float kb[16];
    __shared__ int   kchs[2];

    int kcl[2]; int nk = 0;
    if (s > 0)       kcl[nk++] = s - 1;
    if (s < SEQ - 1) kcl[nk++] = s + 1;
    const int nkeys = nk * 8;

    if (tid < 2 && tid < nk) kchs[tid] = kcl[tid];
    if (tid < 8) qidx[tid] = idx[blk*8 + tid];
    if (tid < 16) {
        if (tid < nkeys) {
            const int v = idx[(b*SEQ + kcl[tid >> 3])*8 + (tid & 7)];
            kidx[tid] = v;
            kb[tid]   = kbv[v];
        } else { kidx[tid] = 0; kb[tid] = 0.f; }
    }
    __syncthreads();

    #pragma unroll
    for (int r = 0; r < 8; ++r)
        *(float4*)&Ps[r][4*tid] = *(const float4*)&P[(long long)qidx[r]*D + 4*tid];
    for (int r = 0; r < 16; ++r)
        if (r < nkeys)
            *(float4*)&Es[r][4*tid] = *(const float4*)&E[(long long)kidx[r]*D + 4*tid];
    __syncthreads();

    const int qp = tid >> 4, ki = tid & 15;
    float acc0 = 0.f, acc1 = 0.f;
    const float* pr0 = Ps[qp];
    const float* pr1 = Ps[qp + 4];
    const float* er  = Es[ki];
    #pragma unroll 4
    for (int d4 = 0; d4 < 64; ++d4) {
        const float4 e  = *(const float4*)&er[4*d4];
        const float4 p0 = *(const float4*)&pr0[4*d4];
        const float4 p1 = *(const float4*)&pr1[4*d4];
        acc0 += p0.x*e.x + p0.y*e.y + p0.z*e.z + p0.w*e.w;
        acc1 += p1.x*e.x + p1.y*e.y + p1.z*e.z + p1.w*e.w;
    }
    const bool kvalid = ki < nkeys;
    const float s0 = kvalid ? (16.f*acc0 + kb[ki]) : -1e30f;
    const float s1 = kvalid ? (16.f*acc1 + kb[ki]) : -1e30f;

    float m0 = s0, m1 = s1;
    #pragma unroll
    for (int st = 1; st < 16; st <<= 1) {
        m0 = fmaxf(m0, __shfl_xor(m0, st, 64));
        m1 = fmaxf(m1, __shfl_xor(m1, st, 64));
    }
    float e0 = kvalid ? __expf(s0 - m0) : 0.f;
    float e1 = kvalid ? __expf(s1 - m1) : 0.f;
    float t0 = e0, t1 = e1;
    #pragma unroll
    for (int st = 1; st < 16; st <<= 1) {
        t0 += __shfl_xor(t0, st, 64);
        t1 += __shfl_xor(t1, st, 64);
    }
    const float a0 = e0 / t0, a1 = e1 / t1;

    float cs = a0 + a1;
    cs += __shfl_xor(cs, 16, 64);
    cs += __shfl_xor(cs, 32, 64);
    if (tid < 16 && kvalid) {
        const int kc   = kchs[tid >> 3];
        const int slot = (kc == s + 1) ? 0 : 1;
        na_part[((b*SEQ + kc)*2 + slot)*8 + (tid & 7)] = cs;
    }
}

/* ============ kernel 5: finalize ============ */
__global__ __launch_bounds__(256) void finalize_kernel(
    const float* __restrict__ E, const int* __restrict__ idx,
    const float* __restrict__ npp, const float* __restrict__ na_part,
    float* __restrict__ out)
{
    const int blk = blockIdx.x;
    const int tid = threadIdx.x;
    __shared__ float ps[8];
    __shared__ int   id8[8];

    if (tid < 8) {
        const long long t = (long long)blk*8 + tid;
        const float ns = na_part[((long long)blk*2 + 0)*8 + tid]
                       + na_part[((long long)blk*2 + 1)*8 + tid];
        ps[tid] = ns * npp[t];
        id8[tid] = idx[t];
    }
    __syncthreads();
    if (tid == 0) {
        float l1 = 0.f;
        #pragma unroll
        for (int r = 0; r < 8; ++r) l1 += fabsf(ps[r]);
        l1 = fmaxf(l1, 1e-12f);
        #pragma unroll
        for (int r = 0; r < 8; ++r) ps[r] /= l1;
    }
    __syncthreads();

    float acc = 0.f;
    #pragma unroll
    for (int r = 0; r < 8; ++r) acc += E[(long long)id8[r]*D + tid] * ps[r];
    out[OUT_SCORED + (long long)blk*D + tid] = acc * 16.f;
    if (tid < 8) out[OUT_PS + (long long)blk*8 + tid] = ps[tid];
}

extern "C" void kernel_launch(void* const* d_in, const int* in_sizes, int n_in,
                              void* d_out, int out_size, void* d_ws, size_t ws_size,
                              hipStream_t stream)
{
    const float* na_pred = (const float*)d_in[2];
    const float* emb     = (const float*)d_in[3];
    const float* Wq      = (const float*)d_in[4];
    const float* bq      = (const float*)d_in[5];
    const float* Wk      = (const float*)d_in[6];
    const float* bk      = (const float*)d_in[7];
    (void)bk;

    char* ws = (char*)d_ws;
    int*   ws_idx = (int*)  (ws + OFF_IDX);
    float* ws_npp = (float*)(ws + OFF_NPP);
    float* ws_M   = (float*)(ws + OFF_M);
    float* ws_w   = (float*)(ws + OFF_W);
    float* ws_P   = (float*)(ws + OFF_P);
    float* ws_np  = (float*)(ws + OFF_NPART);
    float* ws_kbv = (float*)(ws + OFF_KBV);
    float* out    = (float*)d_out;

    topk_kernel<<<ROWS, 256, 0, stream>>>(na_pred, ws_idx, ws_npp, out + OUT_IDX);
    m_kernel<<<D, 256, 0, stream>>>(Wq, Wk, ws_M);
    bias_kernel<<<1, 256, 0, stream>>>(Wk, bq, ws_w);
    kbv_kernel<<<(VOCAB + 3)/4, 256, 0, stream>>>(emb, ws_w, ws_kbv);
    p_kernel<<<(VOCAB + 15)/16, 256, 0, stream>>>(emb, ws_M, ws_P);
    hipMemsetAsync(ws_np, 0, BSZ*SEQ*2*8*sizeof(float), stream);
    attn_kernel<<<ROWS, 64, 0, stream>>>(ws_P, emb, ws_idx, ws_kbv, ws_np);
    finalize_kernel<<<ROWS, 256, 0, stream>>>(emb, ws_idx, ws_npp, ws_np, out);
}

// Round 5
// 133.968 us; speedup vs baseline: 2.4497x; 1.1426x over previous
//
#include <hip/hip_runtime.h>
#include <math.h>

#define TOPK 8
#define D    256
#define VOCAB 5000
#define BSZ  64
#define SEQ  128
#define ROWS (BSZ*SEQ)
#define NF4  (VOCAB/4)      /* 1250 float4 per row */

/* workspace layout (bytes) */
#define OFF_IDX   0          /* int32  ROWS*8 */
#define OFF_NPP   262144     /* f32    ROWS*8 */
#define OFF_M     524288     /* f32    256*256 */
#define OFF_W     787456     /* f32    256 */
#define OFF_P     790528     /* f32    5000*256 */
#define OFF_NPART 5910528    /* f32    BSZ*SEQ*2*8 */
#define OFF_KBV   6434816    /* f32    5000 */

/* d_out layout (floats) */
#define OUT_SCORED 0
#define OUT_PS     2097152
#define OUT_IDX    2162688

typedef unsigned long long u64;
typedef unsigned int u32;

__device__ __forceinline__ float wave_fmax(float v) {
    #pragma unroll
    for (int st = 1; st < 64; st <<= 1) v = fmaxf(v, __shfl_xor(v, st, 64));
    return v;
}
__device__ __forceinline__ float wave_fsum(float v) {
    #pragma unroll
    for (int st = 1; st < 64; st <<= 1) v += __shfl_xor(v, st, 64);
    return v;
}
__device__ __forceinline__ u64 wave_umax(u64 v) {
    #pragma unroll
    for (int st = 1; st < 64; st <<= 1) {
        const u64 o = __shfl_xor(v, st, 64);
        v = (o > v) ? o : v;
    }
    return v;
}
__device__ __forceinline__ u64 pack_key(float x, int idx) {
    u32 bu = __float_as_uint(x);
    u32 key = bu ^ ((u32)((int)bu >> 31) | 0x80000000u);
    return ((u64)key << 32) | (u64)(0xFFFFFFFFu ^ (u32)idx);
}

/* ============ kernel 1: row in registers; filter; exact top-8 ============ */
__global__ __launch_bounds__(256) void topk_kernel(
    const float* __restrict__ na_pred,
    int*  __restrict__ out_idx,
    float* __restrict__ out_npp,
    float* __restrict__ out_idx_f)
{
    __shared__ float tmax[256];
    __shared__ float wsum[4];
    __shared__ float cv[64];
    __shared__ int   ci[64];
    __shared__ int   cnt;
    __shared__ u64   res_s[8];
    __shared__ u64   ured[4];

    const int tid  = threadIdx.x;
    const int lane = tid & 63;
    const int wid  = tid >> 6;
    const long long base = (long long)blockIdx.x * VOCAB;
    const float4* src = (const float4*)(na_pred + base);

    if (tid == 0) cnt = 0;

    /* ---- 20 elements per thread, all loads independent & in flight ---- */
    const int i0 = tid, i1 = tid + 256, i2 = tid + 512, i3 = tid + 768, i4 = tid + 1024;
    const float4 r0 = src[i0];
    const float4 r1 = src[i1];
    const float4 r2 = src[i2];
    const float4 r3 = src[i3];
    const float4 r4 = (i4 < NF4) ? src[i4]
                    : make_float4(-INFINITY, -INFINITY, -INFINITY, -INFINITY);

    /* ---- per-thread max (tree, no dependence on exp) ---- */
    float m01 = fmaxf(fmaxf(r0.x, r0.y), fmaxf(r0.z, r0.w));
    float m23 = fmaxf(fmaxf(r1.x, r1.y), fmaxf(r1.z, r1.w));
    float m45 = fmaxf(fmaxf(r2.x, r2.y), fmaxf(r2.z, r2.w));
    float m67 = fmaxf(fmaxf(r3.x, r3.y), fmaxf(r3.z, r3.w));
    float m89 = fmaxf(fmaxf(r4.x, r4.y), fmaxf(r4.z, r4.w));
    const float m = fmaxf(fmaxf(fmaxf(m01, m23), fmaxf(m45, m67)), m89);
    tmax[tid] = m;
    __syncthreads();

    /* ---- all waves redundantly: rowmax + thr (8th of 64 combined maxes) ---- */
    const float comb = fmaxf(fmaxf(tmax[lane], tmax[lane + 64]),
                             fmaxf(tmax[lane + 128], tmax[lane + 192]));
    const float rowmax = wave_fmax(comb);
    float am = comb, thr = rowmax;
    #pragma unroll
    for (int r = 0; r < 8; ++r) {
        const float cur = wave_fmax(am);
        if (am == cur) am = -INFINITY;
        thr = cur;
    }

    /* ---- sumexp from registers: 20 independent exps ---- */
    float se = 0.f;
    se += __expf(r0.x - rowmax); se += __expf(r0.y - rowmax);
    se += __expf(r0.z - rowmax); se += __expf(r0.w - rowmax);
    se += __expf(r1.x - rowmax); se += __expf(r1.y - rowmax);
    se += __expf(r1.z - rowmax); se += __expf(r1.w - rowmax);
    se += __expf(r2.x - rowmax); se += __expf(r2.y - rowmax);
    se += __expf(r2.z - rowmax); se += __expf(r2.w - rowmax);
    se += __expf(r3.x - rowmax); se += __expf(r3.y - rowmax);
    se += __expf(r3.z - rowmax); se += __expf(r3.w - rowmax);
    se += __expf(r4.x - rowmax); se += __expf(r4.y - rowmax);
    se += __expf(r4.z - rowmax); se += __expf(r4.w - rowmax);
    const float swv = wave_fsum(se);
    if (lane == 0) wsum[wid] = swv;

    /* ---- filter from registers into LDS candidate list ---- */
#define FILT(val, eidx) do { const float x_ = (val); \
    if (x_ >= thr) { const int pos = atomicAdd(&cnt, 1); \
        if (pos < 64) { cv[pos] = x_; ci[pos] = (eidx); } } } while (0)
    FILT(r0.x, 4*i0+0); FILT(r0.y, 4*i0+1); FILT(r0.z, 4*i0+2); FILT(r0.w, 4*i0+3);
    FILT(r1.x, 4*i1+0); FILT(r1.y, 4*i1+1); FILT(r1.z, 4*i1+2); FILT(r1.w, 4*i1+3);
    FILT(r2.x, 4*i2+0); FILT(r2.y, 4*i2+1); FILT(r2.z, 4*i2+2); FILT(r2.w, 4*i2+3);
    FILT(r3.x, 4*i3+0); FILT(r3.y, 4*i3+1); FILT(r3.z, 4*i3+2); FILT(r3.w, 4*i3+3);
    FILT(r4.x, 4*i4+0); FILT(r4.y, 4*i4+1); FILT(r4.z, 4*i4+2); FILT(r4.w, 4*i4+3);
#undef FILT
    __syncthreads();

    const int cntv = cnt;
    if (cntv <= 64) {
        /* fast path: wave 0 selects over <=64 candidates */
        if (tid < 64) {
            u64 key = (tid < cntv) ? pack_key(cv[tid], ci[tid]) : 0ULL;
            #pragma unroll
            for (int r = 0; r < 8; ++r) {
                const u64 mm = wave_umax(key);
                if (key == mm) key = 0ULL;
                if (tid == 0) res_s[r] = mm;
            }
        }
    } else {
        /* exact fallback: block-wide repeated selection from registers */
        u64 last = ~0ULL;
        for (int r = 0; r < 8; ++r) {
            u64 best = 0ULL;
#define CAND(val, eidx) do { const u64 k_ = pack_key((val), (eidx)); \
    if (k_ < last && k_ > best) best = k_; } while (0)
            CAND(r0.x, 4*i0+0); CAND(r0.y, 4*i0+1); CAND(r0.z, 4*i0+2); CAND(r0.w, 4*i0+3);
            CAND(r1.x, 4*i1+0); CAND(r1.y, 4*i1+1); CAND(r1.z, 4*i1+2); CAND(r1.w, 4*i1+3);
            CAND(r2.x, 4*i2+0); CAND(r2.y, 4*i2+1); CAND(r2.z, 4*i2+2); CAND(r2.w, 4*i2+3);
            CAND(r3.x, 4*i3+0); CAND(r3.y, 4*i3+1); CAND(r3.z, 4*i3+2); CAND(r3.w, 4*i3+3);
            CAND(r4.x, 4*i4+0); CAND(r4.y, 4*i4+1); CAND(r4.z, 4*i4+2); CAND(r4.w, 4*i4+3);
#undef CAND
            best = wave_umax(best);
            if (lane == 0) ured[wid] = best;
            __syncthreads();
            u64 b = ured[0];
            #pragma unroll
            for (int wq = 1; wq < 4; ++wq) b = (ured[wq] > b) ? ured[wq] : b;
            if (tid == 0) res_s[r] = b;
            last = b;
            __syncthreads();
        }
    }
    __syncthreads();

    /* ---- 8-lane parallel epilogue ---- */
    if (wid == 0 && lane < 8) {
        const float S = wsum[0] + wsum[1] + wsum[2] + wsum[3];
        const u64 res = res_s[lane];
        const u32 key = (u32)(res >> 32);
        const int ixv = (int)(0xFFFFFFFFu ^ (u32)(res & 0xFFFFFFFFu));
        const u32 bu  = key ^ ((key & 0x80000000u) ? 0x80000000u : 0xFFFFFFFFu);
        const float p = __expf(__uint_as_float(bu) - rowmax) / S;
        float pm = p;
        #pragma unroll
        for (int st = 1; st < 8; st <<= 1) pm = fmaxf(pm, __shfl_xor(pm, st, 64));
        const float q = __expf(p - pm);
        float s2 = q;
        #pragma unroll
        for (int st = 1; st < 8; st <<= 1) s2 += __shfl_xor(s2, st, 64);
        const long long ob = (long long)blockIdx.x * TOPK + lane;
        out_idx[ob]   = ixv;
        out_npp[ob]   = q / s2;
        out_idx_f[ob] = (float)ixv;
    }
}

/* ============ kernel 2: M = Wq @ Wk^T ============ */
__global__ __launch_bounds__(256) void m_kernel(
    const float* __restrict__ Wq, const float* __restrict__ Wk,
    float* __restrict__ M)
{
    __shared__ float qrow[D];
    const int a = blockIdx.x, j = threadIdx.x;
    qrow[j] = Wq[a*D + j];
    __syncthreads();
    float acc = 0.f;
    #pragma unroll 4
    for (int d4 = 0; d4 < 64; ++d4) {
        const float4 wk = *(const float4*)&Wk[j*D + 4*d4];
        const float4 q4 = *(const float4*)&qrow[4*d4];
        acc += wk.x*q4.x + wk.y*q4.y + wk.z*q4.z + wk.w*q4.w;
    }
    M[a*D + j] = acc;
}

/* ============ kernel 2b: w = Wk @ bq ============ */
__global__ __launch_bounds__(256) void bias_kernel(
    const float* __restrict__ Wk, const float* __restrict__ bq,
    float* __restrict__ w)
{
    const int i = threadIdx.x;
    float aw = 0.f;
    #pragma unroll 4
    for (int d4 = 0; d4 < 64; ++d4) {
        const float4 wk = *(const float4*)&Wk[i*D + 4*d4];
        const float4 b4 = *(const float4*)&bq[4*d4];
        aw += wk.x*b4.x + wk.y*b4.y + wk.z*b4.z + wk.w*b4.w;
    }
    w[i] = aw;
}

/* ============ kernel 2c: kbv[v] = E[v] . w ============ */
__global__ __launch_bounds__(256) void kbv_kernel(
    const float* __restrict__ E, const float* __restrict__ w,
    float* __restrict__ kbv)
{
    const int row  = blockIdx.x * 4 + (threadIdx.x >> 6);
    const int lane = threadIdx.x & 63;
    if (row >= VOCAB) return;
    const float4 e  = *(const float4*)&E[(long long)row*D + 4*lane];
    const float4 ww = *(const float4*)&w[4*lane];
    float p = e.x*ww.x + e.y*ww.y + e.z*ww.z + e.w*ww.w;
    #pragma unroll
    for (int st = 1; st < 64; st <<= 1) p += __shfl_xor(p, st, 64);
    if (lane == 0) kbv[row] = p;
}

/* ============ kernel 3: P = E @ M (16 rows/block, 4x4 reg tile) ============ */
__global__ __launch_bounds__(256) void p_kernel(
    const float* __restrict__ E, const float* __restrict__ M,
    float* __restrict__ P)
{
    __shared__ float seT[256][20];
    const int tid = threadIdx.x;
    const int r0  = blockIdx.x * 16;
    {
        const int r = tid >> 4, d4b = tid & 15;
        const bool ok = (r0 + r) < VOCAB;
        #pragma unroll
        for (int k = 0; k < 4; ++k) {
            const int d4 = d4b + 16*k;
            float4 v = make_float4(0.f, 0.f, 0.f, 0.f);
            if (ok) v = *(const float4*)&E[(long long)(r0+r)*D + 4*d4];
            seT[4*d4+0][r] = v.x; seT[4*d4+1][r] = v.y;
            seT[4*d4+2][r] = v.z; seT[4*d4+3][r] = v.w;
        }
    }
    __syncthreads();
    const int rg = tid >> 6, j4 = tid & 63;
    float acc[4][4];
    #pragma unroll
    for (int i = 0; i < 4; ++i)
        { acc[i][0]=0.f; acc[i][1]=0.f; acc[i][2]=0.f; acc[i][3]=0.f; }
    #pragma unroll 4
    for (int d = 0; d < 256; ++d) {
        const float4 m4 = *(const float4*)&M[d*D + 4*j4];
        const float4 s4 = *(const float4*)&seT[d][4*rg];
        const float ss[4] = {s4.x, s4.y, s4.z, s4.w};
        #pragma unroll
        for (int rr = 0; rr < 4; ++rr) {
            acc[rr][0] += ss[rr]*m4.x; acc[rr][1] += ss[rr]*m4.y;
            acc[rr][2] += ss[rr]*m4.z; acc[rr][3] += ss[rr]*m4.w;
        }
    }
    #pragma unroll
    for (int rr = 0; rr < 4; ++rr) {
        const int row = r0 + 4*rg + rr;
        if (row < VOCAB) {
            float4 o;
            o.x = acc[rr][0]; o.y = acc[rr][1]; o.z = acc[rr][2]; o.w = acc[rr][3];
            *(float4*)&P[(long long)row*D + 4*j4] = o;
        }
    }
}

/* ============ kernel 4: masked block attention (1 wave / chunk) ============ */
__global__ __launch_bounds__(64) void attn_kernel(
    const float* __restrict__ P, const float* __restrict__ E,
    const int*  __restrict__ idx, const float* __restrict__ kbv,
    float* __restrict__ na_part /* (BSZ,SEQ,2,8) */)
{
    const int blk = blockIdx.x;
    const int b = blk >> 7, s = blk & 127;
    const int tid = threadIdx.x;

    __shared__ float Ps[8][260];
    __shared__ float Es[16][260];
    __shared__ int   qidx[8];
    __shared__ int   kidx[16];
    __shared__ float kb[16];
    __shared__ int   kchs[2];

    int kcl[2]; int nk = 0;
    if (s > 0)       kcl[nk++] = s - 1;
    if (s < SEQ - 1) kcl[nk++] = s + 1;
    const int nkeys = nk * 8;

    if (tid < 2 && tid < nk) kchs[tid] = kcl[tid];
    if (tid < 8) qidx[tid] = idx[blk*8 + tid];
    if (tid < 16) {
        if (tid < nkeys) {
            const int v = idx[(b*SEQ + kcl[tid >> 3])*8 + (tid & 7)];
            kidx[tid] = v;
            kb[tid]   = kbv[v];
        } else { kidx[tid] = 0; kb[tid] = 0.f; }
    }
    __syncthreads();

    #pragma unroll
    for (int r = 0; r < 8; ++r)
        *(float4*)&Ps[r][4*tid] = *(const float4*)&P[(long long)qidx[r]*D + 4*tid];
    for (int r = 0; r < 16; ++r)
        if (r < nkeys)
            *(float4*)&Es[r][4*tid] = *(const float4*)&E[(long long)kidx[r]*D + 4*tid];
    __syncthreads();

    const int qp = tid >> 4, ki = tid & 15;
    float acc0 = 0.f, acc1 = 0.f;
    const float* pr0 = Ps[qp];
    const float* pr1 = Ps[qp + 4];
    const float* er  = Es[ki];
    #pragma unroll 4
    for (int d4 = 0; d4 < 64; ++d4) {
        const float4 e  = *(const float4*)&er[4*d4];
        const float4 p0 = *(const float4*)&pr0[4*d4];
        const float4 p1 = *(const float4*)&pr1[4*d4];
        acc0 += p0.x*e.x + p0.y*e.y + p0.z*e.z + p0.w*e.w;
        acc1 += p1.x*e.x + p1.y*e.y + p1.z*e.z + p1.w*e.w;
    }
    const bool kvalid = ki < nkeys;
    const float s0 = kvalid ? (16.f*acc0 + kb[ki]) : -1e30f;
    const float s1 = kvalid ? (16.f*acc1 + kb[ki]) : -1e30f;

    float m0 = s0, m1 = s1;
    #pragma unroll
    for (int st = 1; st < 16; st <<= 1) {
        m0 = fmaxf(m0, __shfl_xor(m0, st, 64));
        m1 = fmaxf(m1, __shfl_xor(m1, st, 64));
    }
    float e0 = kvalid ? __expf(s0 - m0) : 0.f;
    float e1 = kvalid ? __expf(s1 - m1) : 0.f;
    float t0 = e0, t1 = e1;
    #pragma unroll
    for (int st = 1; st < 16; st <<= 1) {
        t0 += __shfl_xor(t0, st, 64);
        t1 += __shfl_xor(t1, st, 64);
    }
    const float a0 = e0 / t0, a1 = e1 / t1;

    float cs = a0 + a1;
    cs += __shfl_xor(cs, 16, 64);
    cs += __shfl_xor(cs, 32, 64);
    if (tid < 16 && kvalid) {
        const int kc   = kchs[tid >> 3];
        const int slot = (kc == s + 1) ? 0 : 1;
        na_part[((b*SEQ + kc)*2 + slot)*8 + (tid & 7)] = cs;
    }
}

/* ============ kernel 5: finalize ============ */
__global__ __launch_bounds__(256) void finalize_kernel(
    const float* __restrict__ E, const int* __restrict__ idx,
    const float* __restrict__ npp, const float* __restrict__ na_part,
    float* __restrict__ out)
{
    const int blk = blockIdx.x;
    const int tid = threadIdx.x;
    __shared__ float ps[8];
    __shared__ int   id8[8];

    if (tid < 8) {
        const long long t = (long long)blk*8 + tid;
        const float ns = na_part[((long long)blk*2 + 0)*8 + tid]
                       + na_part[((long long)blk*2 + 1)*8 + tid];
        ps[tid] = ns * npp[t];
        id8[tid] = idx[t];
    }
    __syncthreads();
    if (tid == 0) {
        float l1 = 0.f;
        #pragma unroll
        for (int r = 0; r < 8; ++r) l1 += fabsf(ps[r]);
        l1 = fmaxf(l1, 1e-12f);
        #pragma unroll
        for (int r = 0; r < 8; ++r) ps[r] /= l1;
    }
    __syncthreads();

    float acc = 0.f;
    #pragma unroll
    for (int r = 0; r < 8; ++r) acc += E[(long long)id8[r]*D + tid] * ps[r];
    out[OUT_SCORED + (long long)blk*D + tid] = acc * 16.f;
    if (tid < 8) out[OUT_PS + (long long)blk*8 + tid] = ps[tid];
}

extern "C" void kernel_launch(void* const* d_in, const int* in_sizes, int n_in,
                              void* d_out, int out_size, void* d_ws, size_t ws_size,
                              hipStream_t stream)
{
    const float* na_pred = (const float*)d_in[2];
    const float* emb     = (const float*)d_in[3];
    const float* Wq      = (const float*)d_in[4];
    const float* bq      = (const float*)d_in[5];
    const float* Wk      = (const float*)d_in[6];
    const float* bk      = (const float*)d_in[7];
    (void)bk;

    char* ws = (char*)d_ws;
    int*   ws_idx = (int*)  (ws + OFF_IDX);
    float* ws_npp = (float*)(ws + OFF_NPP);
    float* ws_M   = (float*)(ws + OFF_M);
    float* ws_w   = (float*)(ws + OFF_W);
    float* ws_P   = (float*)(ws + OFF_P);
    float* ws_np  = (float*)(ws + OFF_NPART);
    float* ws_kbv = (float*)(ws + OFF_KBV);
    float* out    = (float*)d_out;

    topk_kernel<<<ROWS, 256, 0, stream>>>(na_pred, ws_idx, ws_npp, out + OUT_IDX);
    m_kernel<<<D, 256, 0, stream>>>(Wq, Wk, ws_M);
    bias_kernel<<<1, 256, 0, stream>>>(Wk, bq, ws_w);
    kbv_kernel<<<(VOCAB + 3)/4, 256, 0, stream>>>(emb, ws_w, ws_kbv);
    p_kernel<<<(VOCAB + 15)/16, 256, 0, stream>>>(emb, ws_M, ws_P);
    hipMemsetAsync(ws_np, 0, BSZ*SEQ*2*8*sizeof(float), stream);
    attn_kernel<<<ROWS, 64, 0, stream>>>(ws_P, emb, ws_idx, ws_kbv, ws_np);
    finalize_kernel<<<ROWS, 256, 0, stream>>>(emb, ws_idx, ws_npp, ws_np, out);
}